// Round 7
// baseline (203.615 us; speedup 1.0000x reference)
//
#include <hip/hip_runtime.h>
#include <stdint.h>

#define Bq 4096
#define Tq 200
#define TP 208      // padded to 13 tiles of 16
#define NMT 13
#define Vq 100000
#define BPB 8       // b's per k_weff block
#define NW 8        // waves in k_attn_fast

typedef __attribute__((ext_vector_type(8))) short short8;   // 8 bf16 in 4 VGPRs
typedef __attribute__((ext_vector_type(4))) float f32x4;
typedef __attribute__((ext_vector_type(4))) unsigned short bfx4;
typedef __attribute__((ext_vector_type(4))) unsigned int u32x4;

static __device__ __forceinline__ unsigned short f2b(float f) {
    unsigned int u = __builtin_bit_cast(unsigned int, f);
    u = u + 0x7fffu + ((u >> 16) & 1u);            // RNE
    return (unsigned short)(u >> 16);
}
static __device__ __forceinline__ float b2f(unsigned short s) {
    unsigned int u = ((unsigned int)s) << 16;
    return __builtin_bit_cast(float, u);
}
// 2x f32 -> packed bf16 (RNE), single HW instr
static __device__ __forceinline__ unsigned int pack2(float lo, float hi) {
    unsigned int r;
    asm volatile("v_cvt_pk_bf16_f32 %0, %1, %2" : "=v"(r) : "v"(lo), "v"(hi));
    return r;
}

// swizzled [R][64]-bf16 tile helpers: byte = (row*128 + col*2) ^ ((row&7)<<4)
static __device__ __forceinline__ short8 ld8sw(const unsigned short* base, int row, int col8) {
    return *(const short8*)((const char*)base + (((row << 7) + (col8 << 1)) ^ ((row & 7) << 4)));
}
static __device__ __forceinline__ void st16sw(unsigned short* base, int row, int col, unsigned short v) {
    *(unsigned short*)((char*)base + (((row << 7) + (col << 1)) ^ ((row & 7) << 4))) = v;
}
static __device__ __forceinline__ void st64sw(unsigned short* base, int row, int col4, bfx4 v) {
    *(bfx4*)((char*)base + (((row << 7) + (col4 << 3)) ^ ((row & 7) << 4))) = v;
}
static __device__ __forceinline__ void st128sw(unsigned short* base, int row, int col8, short8 v) {
    *(short8*)((char*)base + (((row << 7) + (col8 << 1)) ^ ((row & 7) << 4))) = v;
}

// ---------------- K0: per-b effective weights (+ bf16 embed table append) ----------------
extern "C" __global__ __launch_bounds__(256) void k_weff(
    const int* __restrict__ target, const float* __restrict__ embed,
    const float* __restrict__ aw1, const float* __restrict__ ab1,
    const float* __restrict__ aw2,
    unsigned short* __restrict__ weff_all, float* __restrict__ qc_all,
    unsigned short* __restrict__ aw2t, unsigned short* __restrict__ embf)
{
    __shared__ float s_C[64][64];    // [i][j]
    __shared__ float s_W3[64][64];   // [i][j]
    __shared__ float s_W12T[64][64]; // [j][i]
    __shared__ float s_qb[BPB][64];
    int tid = threadIdx.x;
    int b0 = blockIdx.x * BPB;

    for (int idx = tid; idx < 4096; idx += 256) {
        int i = idx >> 6, j = idx & 63;
        float a0 = aw1[i * 64 + j];
        float a1 = aw1[(64 + i) * 64 + j];
        float a2 = aw1[(128 + i) * 64 + j];
        float a3 = aw1[(192 + i) * 64 + j];
        s_C[i][j] = a0 + a2;
        s_W3[i][j] = a3;
        s_W12T[j][i] = a1 - a2;
    }
    for (int idx = tid; idx < BPB * 64; idx += 256) {
        int bb = idx >> 6, j = idx & 63;
        s_qb[bb][j] = embed[(long)target[b0 + bb] * 64 + j];
    }
    if (blockIdx.x == 0) {
        for (int idx = tid; idx < 2048; idx += 256) {
            int j = idx >> 5, k = idx & 31;
            aw2t[k * 64 + j] = f2b(aw2[j * 32 + k]);
        }
    }
    __syncthreads();

    // qc
    for (int p = tid; p < BPB * 64; p += 256) {
        int bb = p >> 6, j = p & 63;
        float acc = ab1[j];
        #pragma unroll
        for (int i4 = 0; i4 < 64; i4 += 4) {
            f32x4 qv = *(const f32x4*)&s_qb[bb][i4];
            f32x4 wv = *(const f32x4*)&s_W12T[j][i4];
            acc += qv.x * wv.x + qv.y * wv.y + qv.z * wv.z + qv.w * wv.w;
        }
        qc_all[(long)(b0 + bb) * 64 + j] = acc;
    }
    // weff: thread owns (j = tid>>2, i0 = (tid&3)*16)
    int jw = tid >> 2, i0 = (tid & 3) << 4;
    for (int bb = 0; bb < BPB; ++bb) {
        unsigned int pk[8];
        #pragma unroll
        for (int u = 0; u < 8; ++u) {
            int i = i0 + u * 2;
            float w0 = s_C[i][jw] + s_qb[bb][i] * s_W3[i][jw];
            float w1 = s_C[i + 1][jw] + s_qb[bb][i + 1] * s_W3[i + 1][jw];
            pk[u] = pack2(w0, w1);
        }
        u32x4* dst = (u32x4*)(weff_all + (((long)(b0 + bb)) << 12) + jw * 64 + i0);
        u32x4 v0 = { pk[0], pk[1], pk[2], pk[3] };
        u32x4 v1 = { pk[4], pk[5], pk[6], pk[7] };
        dst[0] = v0;
        dst[1] = v1;
    }
    // bf16 embed table (grid-stride append; independent of the above)
    if (embf) {
        long gsz = (long)gridDim.x * 256;
        for (long i = (long)blockIdx.x * 256 + tid; i < (long)Vq * 8; i += gsz) {
            const float* src = embed + i * 8;
            f32x4 e0 = *(const f32x4*)src;
            f32x4 e1 = *(const f32x4*)(src + 4);
            u32x4 pk = { pack2(e0.x, e0.y), pack2(e0.z, e0.w),
                         pack2(e1.x, e1.y), pack2(e1.z, e1.w) };
            *(u32x4*)(embf + i * 8) = pk;
        }
    }
}

// ---------------- KA fast: fused attention -> interest[b][64], 8 waves ----------------
extern "C" __global__ __launch_bounds__(512, 6) void k_attn_fast(
    const int* __restrict__ hist, const int* __restrict__ mask,
    const float* __restrict__ embed,
    const float* __restrict__ ab2, const float* __restrict__ aow,
    const float* __restrict__ aob,
    const unsigned short* __restrict__ weff_all,
    const float* __restrict__ qc_all,
    const unsigned short* __restrict__ aw2t,
    const unsigned short* __restrict__ embf,
    float* __restrict__ inter64)
{
    __shared__ int s_id[TP];
    __shared__ alignas(16) unsigned short s_hist[TP * 64];     // bf16, swizzled
    __shared__ alignas(16) unsigned short s_h1[NW * 16 * 64];  // per-wave scratch, swizzled
    __shared__ float s_sc[TP];
    __shared__ float s_red[2 * NW];
    __shared__ float s_intp[NW][64];

    int tid = threadIdx.x;
    int lane = tid & 63;
    int wv = tid >> 6;
    int b = blockIdx.x;
    int r16 = lane & 15;
    int kg = lane >> 4;

    // issue all B-fragment / constant loads up front (no LDS dependency -> latency hidden)
    short8 wf[4][2];
    #pragma unroll
    for (int n = 0; n < 4; ++n)
        #pragma unroll
        for (int h = 0; h < 2; ++h)
            wf[n][h] = *(const short8*)(weff_all + (((long)b) << 12) + (n * 16 + r16) * 64 + h * 32 + kg * 8);
    short8 af[2][2];
    #pragma unroll
    for (int n = 0; n < 2; ++n)
        #pragma unroll
        for (int h = 0; h < 2; ++h)
            af[n][h] = *(const short8*)(aw2t + (n * 16 + r16) * 64 + h * 32 + kg * 8);
    f32x4 qcz[4];
    #pragma unroll
    for (int n = 0; n < 4; ++n) {
        float v = qc_all[(long)b * 64 + n * 16 + r16];
        qcz[n].x = v; qcz[n].y = v; qcz[n].z = v; qcz[n].w = v;
    }
    float ab2a = ab2[r16], ab2b = ab2[16 + r16];
    float aowa = aow[r16], aowb = aow[16 + r16];
    float aob0 = aob[0];

    for (int t = tid; t < TP; t += 512) s_id[t] = hist[b * Tq + ((t < Tq) ? t : 0)];
    __syncthreads();

    // stage hist rows as bf16 (uniform branch on embf availability)
    if (embf) {
        for (int u = tid; u < TP * 8; u += 512) {
            int t = u >> 3, c = u & 7;
            short8 v = *(const short8*)(embf + (long)s_id[t] * 64 + c * 8);
            st128sw(s_hist, t, c * 8, v);
        }
    } else {
        for (int u = tid; u < TP * 8; u += 512) {
            int t = u >> 3, c = u & 7;
            const float* src = &embed[(long)s_id[t] * 64 + c * 8];
            f32x4 e0 = *(const f32x4*)src;
            f32x4 e1 = *(const f32x4*)(src + 4);
            u32x4 pk = { pack2(e0.x, e0.y), pack2(e0.z, e0.w),
                         pack2(e1.x, e1.y), pack2(e1.z, e1.w) };
            *(u32x4*)((char*)s_hist + (((t << 7) + (c << 4)) ^ ((t & 7) << 4))) = pk;
        }
    }
    __syncthreads();

    unsigned short* h1w = s_h1 + wv * 16 * 64;

    // scores: per-wave private M-tiles, no barriers inside
    for (int m = wv; m < NMT; m += NW) {
        int row0 = m * 16;
        short8 a0 = ld8sw(s_hist, row0 + r16, kg * 8);
        short8 a1 = ld8sw(s_hist, row0 + r16, 32 + kg * 8);
        f32x4 d[4];
        #pragma unroll
        for (int n = 0; n < 4; ++n) {
            f32x4 z = qcz[n];
            z = __builtin_amdgcn_mfma_f32_16x16x32_bf16(a0, wf[n][0], z, 0, 0, 0);
            z = __builtin_amdgcn_mfma_f32_16x16x32_bf16(a1, wf[n][1], z, 0, 0, 0);
            d[n] = z;
        }
        // h1 = relu(.)  D layout: col=lane&15, row=(lane>>4)*4+r
        #pragma unroll
        for (int n = 0; n < 4; ++n) {
            int col = n * 16 + r16;
            #pragma unroll
            for (int r = 0; r < 4; ++r)
                st16sw(h1w, kg * 4 + r, col, f2b(fmaxf(d[n][r], 0.f)));
        }
        short8 ha0 = ld8sw(h1w, r16, kg * 8);
        short8 ha1 = ld8sw(h1w, r16, 32 + kg * 8);
        f32x4 e[2];
        #pragma unroll
        for (int n = 0; n < 2; ++n) {
            f32x4 z = { 0.f, 0.f, 0.f, 0.f };
            z = __builtin_amdgcn_mfma_f32_16x16x32_bf16(ha0, af[n][0], z, 0, 0, 0);
            z = __builtin_amdgcn_mfma_f32_16x16x32_bf16(ha1, af[n][1], z, 0, 0, 0);
            e[n] = z;
        }
        #pragma unroll
        for (int r = 0; r < 4; ++r) {
            float h20 = fmaxf(e[0][r] + ab2a, 0.f);
            float h21 = fmaxf(e[1][r] + ab2b, 0.f);
            float p = h20 * aowa + h21 * aowb;
            p += __shfl_xor(p, 1);
            p += __shfl_xor(p, 2);
            p += __shfl_xor(p, 4);
            p += __shfl_xor(p, 8);
            if (r16 == 0) s_sc[row0 + kg * 4 + r] = p + aob0;
        }
    }
    __syncthreads();

    // softmax over t<200 (masked; mask is int32). tid>=256 waves hold neutral values.
    float sc = -1e30f;
    if (tid < Tq) {
        int mk = mask[(long)b * Tq + tid];
        sc = mk ? s_sc[tid] : -1e9f;
    }
    float mx = sc;
    #pragma unroll
    for (int off = 1; off < 64; off <<= 1) mx = fmaxf(mx, __shfl_xor(mx, off));
    if (lane == 0) s_red[wv] = mx;
    __syncthreads();
    mx = s_red[0];
    #pragma unroll
    for (int w = 1; w < NW; ++w) mx = fmaxf(mx, s_red[w]);
    float ex = (tid < Tq) ? expf(sc - mx) : 0.f;
    float sm = ex;
    #pragma unroll
    for (int off = 1; off < 64; off <<= 1) sm += __shfl_xor(sm, off);
    if (lane == 0) s_red[NW + wv] = sm;
    __syncthreads();
    float tot = s_red[NW];
    #pragma unroll
    for (int w = 1; w < NW; ++w) tot += s_red[NW + w];
    if (tid < Tq) s_sc[tid] = ex / tot;
    else if (tid < TP) s_sc[tid] = 0.f;
    __syncthreads();

    // interest: 8 rows x 8 col-groups per wave-op, wide conflict-free LDS reads
    int cg = lane & 7;   // cols cg*8..+7
    int tg = lane >> 3;  // row within 8-row group
    float acc8[8];
    #pragma unroll
    for (int u = 0; u < 8; ++u) acc8[u] = 0.f;
    for (int t = wv * 8 + tg; t < TP; t += 64) {
        float w = s_sc[t];
        short8 h = ld8sw(s_hist, t, cg * 8);
        #pragma unroll
        for (int u = 0; u < 8; ++u) acc8[u] += w * b2f((unsigned short)h[u]);
    }
    #pragma unroll
    for (int u = 0; u < 8; ++u) {
        acc8[u] += __shfl_xor(acc8[u], 8);
        acc8[u] += __shfl_xor(acc8[u], 16);
        acc8[u] += __shfl_xor(acc8[u], 32);
    }
    if (tg == 0) {
        #pragma unroll
        for (int u = 0; u < 8; ++u) s_intp[wv][cg * 8 + u] = acc8[u];
    }
    __syncthreads();
    if (tid < 64) {
        float s = s_intp[0][tid];
        #pragma unroll
        for (int w = 1; w < NW; ++w) s += s_intp[w][tid];
        inter64[(long)b * 64 + tid] = s;
    }
}

// ---------------- KA fallback (round-5 proven path, used if ws too small) ----------------
extern "C" __global__ __launch_bounds__(256, 3) void k_attn_fb(
    const int* __restrict__ target, const int* __restrict__ hist,
    const int* __restrict__ mask,
    const float* __restrict__ embed, const float* __restrict__ aw1,
    const float* __restrict__ ab1, const float* __restrict__ aw2,
    const float* __restrict__ ab2, const float* __restrict__ aow,
    const float* __restrict__ aob,
    float* __restrict__ inter64)
{
    __shared__ int s_id[TP];
    __shared__ float s_q[64];
    __shared__ float s_qc[64];
    __shared__ float s_qcp[4][64];
    __shared__ alignas(16) unsigned short s_hist[TP * 64];
    __shared__ alignas(16) unsigned short s_WeffT[64 * 64];
    __shared__ alignas(16) unsigned short s_aw2T[32 * 64];
    __shared__ alignas(16) unsigned short s_h1[4 * 16 * 64];
    __shared__ float s_sc[TP];
    __shared__ float s_aow[32];
    __shared__ float s_ab2[32];
    __shared__ float s_red[8];
    __shared__ float s_intp[4][64];

    int tid = threadIdx.x;
    int lane = tid & 63;
    int wv = tid >> 6;
    int b = blockIdx.x;

    int tgt = target[b];
    if (tid < 64) s_q[tid] = embed[(long)tgt * 64 + tid];
    for (int t = tid; t < TP; t += 256) s_id[t] = hist[b * Tq + ((t < Tq) ? t : 0)];
    if (tid < 32) { s_aow[tid] = aow[tid]; s_ab2[tid] = ab2[tid]; }
    __syncthreads();

    for (int idx = tid; idx < 4096; idx += 256) {
        int i = idx >> 6, j = idx & 63;
        float w = aw1[i * 64 + j] + aw1[(128 + i) * 64 + j] + s_q[i] * aw1[(192 + i) * 64 + j];
        st16sw(s_WeffT, j, i, f2b(w));
    }
    for (int idx = tid; idx < 2048; idx += 256) {
        int j = idx >> 5, k = idx & 31;
        st16sw(s_aw2T, k, j, f2b(aw2[j * 32 + k]));
    }
    {
        float acc = 0.f;
        #pragma unroll
        for (int ii = 0; ii < 16; ++ii) {
            int i = wv * 16 + ii;
            acc += s_q[i] * (aw1[(64 + i) * 64 + lane] - aw1[(128 + i) * 64 + lane]);
        }
        s_qcp[wv][lane] = acc;
    }
    for (int u = tid; u < TP * 16; u += 256) {
        int t = u >> 4, j4 = u & 15;
        f32x4 e = *(const f32x4*)&embed[(long)s_id[t] * 64 + j4 * 4];
        bfx4 p = { f2b(e.x), f2b(e.y), f2b(e.z), f2b(e.w) };
        st64sw(s_hist, t, j4, p);
    }
    __syncthreads();
    if (tid < 64) s_qc[tid] = ab1[tid] + s_qcp[0][tid] + s_qcp[1][tid] + s_qcp[2][tid] + s_qcp[3][tid];
    __syncthreads();

    int r16 = lane & 15;
    int kg = lane >> 4;
    float aob0 = aob[0];
    unsigned short* h1w = s_h1 + wv * 16 * 64;

    for (int m = wv; m < NMT; m += 4) {
        int row0 = m * 16;
        short8 a0 = ld8sw(s_hist, row0 + r16, kg * 8);
        short8 a1 = ld8sw(s_hist, row0 + r16, 32 + kg * 8);
        f32x4 d[4];
        #pragma unroll
        for (int n = 0; n < 4; ++n) {
            short8 b0 = ld8sw(s_WeffT, n * 16 + r16, kg * 8);
            short8 b1 = ld8sw(s_WeffT, n * 16 + r16, 32 + kg * 8);
            float qcv = s_qc[n * 16 + r16];
            f32x4 z = { qcv, qcv, qcv, qcv };
            z = __builtin_amdgcn_mfma_f32_16x16x32_bf16(a0, b0, z, 0, 0, 0);
            z = __builtin_amdgcn_mfma_f32_16x16x32_bf16(a1, b1, z, 0, 0, 0);
            d[n] = z;
        }
        #pragma unroll
        for (int n = 0; n < 4; ++n) {
            int col = n * 16 + r16;
            #pragma unroll
            for (int r = 0; r < 4; ++r)
                st16sw(h1w, kg * 4 + r, col, f2b(fmaxf(d[n][r], 0.f)));
        }
        short8 ha0 = ld8sw(h1w, r16, kg * 8);
        short8 ha1 = ld8sw(h1w, r16, 32 + kg * 8);
        f32x4 e[2];
        #pragma unroll
        for (int n = 0; n < 2; ++n) {
            short8 b0 = ld8sw(s_aw2T, n * 16 + r16, kg * 8);
            short8 b1 = ld8sw(s_aw2T, n * 16 + r16, 32 + kg * 8);
            f32x4 z = { 0.f, 0.f, 0.f, 0.f };
            z = __builtin_amdgcn_mfma_f32_16x16x32_bf16(ha0, b0, z, 0, 0, 0);
            z = __builtin_amdgcn_mfma_f32_16x16x32_bf16(ha1, b1, z, 0, 0, 0);
            e[n] = z;
        }
        #pragma unroll
        for (int r = 0; r < 4; ++r) {
            float h20 = fmaxf(e[0][r] + s_ab2[r16], 0.f);
            float h21 = fmaxf(e[1][r] + s_ab2[16 + r16], 0.f);
            float p = h20 * s_aow[r16] + h21 * s_aow[16 + r16];
            p += __shfl_xor(p, 1);
            p += __shfl_xor(p, 2);
            p += __shfl_xor(p, 4);
            p += __shfl_xor(p, 8);
            if (r16 == 0) s_sc[row0 + kg * 4 + r] = p + aob0;
        }
    }
    __syncthreads();

    float sc = -1e30f;
    if (tid < Tq) {
        int mk = mask[(long)b * Tq + tid];
        sc = mk ? s_sc[tid] : -1e9f;
    }
    float mx = sc;
    #pragma unroll
    for (int off = 1; off < 64; off <<= 1) mx = fmaxf(mx, __shfl_xor(mx, off));
    if (lane == 0) s_red[wv] = mx;
    __syncthreads();
    mx = fmaxf(fmaxf(s_red[0], s_red[1]), fmaxf(s_red[2], s_red[3]));
    float ex = (tid < Tq) ? expf(sc - mx) : 0.f;
    float sm = ex;
    #pragma unroll
    for (int off = 1; off < 64; off <<= 1) sm += __shfl_xor(sm, off);
    if (lane == 0) s_red[4 + wv] = sm;
    __syncthreads();
    float tot = s_red[4] + s_red[5] + s_red[6] + s_red[7];
    if (tid < Tq) s_sc[tid] = ex / tot;
    __syncthreads();

    float acc = 0.f;
    for (int t = wv; t < Tq; t += 4)
        acc += s_sc[t] * b2f(*(const unsigned short*)((const char*)s_hist +
                 (((t << 7) + (lane << 1)) ^ ((t & 7) << 4))));
    s_intp[wv][lane] = acc;
    __syncthreads();
    if (tid < 64)
        inter64[(long)b * 64 + tid] = s_intp[0][tid] + s_intp[1][tid] + s_intp[2][tid] + s_intp[3][tid];
}

// ---------------- KB: final MLP [q | interest] 128->256->128->1, fp32, 8 rows/block ----------------
extern "C" __global__ __launch_bounds__(256) void k_final(
    const int* __restrict__ target, const float* __restrict__ embed,
    const float* __restrict__ inter64, const float* __restrict__ mw1,
    const float* __restrict__ mb1, const float* __restrict__ mw2,
    const float* __restrict__ mb2, const float* __restrict__ ow,
    const float* __restrict__ ob, float* __restrict__ out)
{
    __shared__ alignas(16) float s_in[8][128];
    __shared__ alignas(16) float s_g1[8][256];
    __shared__ alignas(16) float s_g2[8][128];
    int tid = threadIdx.x;
    long b0 = (long)blockIdx.x * 8;
    for (int idx = tid; idx < 1024; idx += 256) {
        int r = idx >> 7, c = idx & 127;
        s_in[r][c] = (c < 64) ? embed[(long)target[b0 + r] * 64 + c]
                              : inter64[(b0 + r) * 64 + (c - 64)];
    }
    __syncthreads();
    {
        float acc[8];
        float bias = mb1[tid];
        #pragma unroll
        for (int r = 0; r < 8; ++r) acc[r] = bias;
        for (int i0 = 0; i0 < 128; i0 += 4) {
            float w0 = mw1[(i0 + 0) * 256 + tid];
            float w1 = mw1[(i0 + 1) * 256 + tid];
            float w2 = mw1[(i0 + 2) * 256 + tid];
            float w3 = mw1[(i0 + 3) * 256 + tid];
            #pragma unroll
            for (int r = 0; r < 8; ++r) {
                f32x4 e = *(const f32x4*)&s_in[r][i0];
                acc[r] += e.x * w0 + e.y * w1 + e.z * w2 + e.w * w3;
            }
        }
        #pragma unroll
        for (int r = 0; r < 8; ++r) s_g1[r][tid] = fmaxf(acc[r], 0.f);
    }
    __syncthreads();
    {
        int o = tid & 127, rh = tid >> 7;   // rows rh*4..rh*4+3
        float acc[4];
        float bias = mb2[o];
        #pragma unroll
        for (int r = 0; r < 4; ++r) acc[r] = bias;
        for (int i0 = 0; i0 < 256; i0 += 4) {
            float w0 = mw2[(i0 + 0) * 128 + o];
            float w1 = mw2[(i0 + 1) * 128 + o];
            float w2 = mw2[(i0 + 2) * 128 + o];
            float w3 = mw2[(i0 + 3) * 128 + o];
            #pragma unroll
            for (int r = 0; r < 4; ++r) {
                f32x4 e = *(const f32x4*)&s_g1[rh * 4 + r][i0];
                acc[r] += e.x * w0 + e.y * w1 + e.z * w2 + e.w * w3;
            }
        }
        #pragma unroll
        for (int r = 0; r < 4; ++r) s_g2[rh * 4 + r][o] = fmaxf(acc[r], 0.f);
    }
    __syncthreads();
    {
        int r = tid >> 5, l32 = tid & 31;
        float acc = 0.f;
        #pragma unroll
        for (int k = 0; k < 4; ++k) acc += s_g2[r][l32 + k * 32] * ow[l32 + k * 32];
        acc += __shfl_xor(acc, 1);
        acc += __shfl_xor(acc, 2);
        acc += __shfl_xor(acc, 4);
        acc += __shfl_xor(acc, 8);
        acc += __shfl_xor(acc, 16);
        if (l32 == 0) out[b0 + r] = acc + ob[0];
    }
}

extern "C" void kernel_launch(void* const* d_in, const int* in_sizes, int n_in,
                              void* d_out, int out_size, void* d_ws, size_t ws_size,
                              hipStream_t stream)
{
    const int*   target = (const int*)d_in[0];
    const int*   hist   = (const int*)d_in[1];
    const int*   mask   = (const int*)d_in[2];
    const float* embed  = (const float*)d_in[3];
    const float* aw1    = (const float*)d_in[4];
    const float* ab1    = (const float*)d_in[5];
    const float* aw2    = (const float*)d_in[6];
    const float* ab2    = (const float*)d_in[7];
    const float* aow    = (const float*)d_in[8];
    const float* aob    = (const float*)d_in[9];
    const float* mw1    = (const float*)d_in[10];
    const float* mb1    = (const float*)d_in[11];
    const float* mw2    = (const float*)d_in[12];
    const float* mb2    = (const float*)d_in[13];
    const float* ow     = (const float*)d_in[14];
    const float* ob     = (const float*)d_in[15];
    float* out = (float*)d_out;

    const size_t WEFF_B = (size_t)Bq * 4096 * 2;     // 32 MB
    const size_t QC_B   = (size_t)Bq * 64 * 4;       // 1 MB
    const size_t AW2T_B = 4096;                      // 4 KB
    const size_t EMBF_B = (size_t)Vq * 64 * 2;       // 12.8 MB
    const size_t INT_B  = (size_t)Bq * 64 * 4;       // 1 MB
    char* p = (char*)d_ws;

    if (ws_size >= WEFF_B + QC_B + AW2T_B + EMBF_B + INT_B) {
        unsigned short* weff  = (unsigned short*)p;
        float*          qc    = (float*)(p + WEFF_B);
        unsigned short* aw2t  = (unsigned short*)(p + WEFF_B + QC_B);
        unsigned short* embf  = (unsigned short*)(p + WEFF_B + QC_B + AW2T_B);
        float*          inter = (float*)(p + WEFF_B + QC_B + AW2T_B + EMBF_B);
        k_weff<<<Bq / BPB, 256, 0, stream>>>(target, embed, aw1, ab1, aw2, weff, qc, aw2t, embf);
        k_attn_fast<<<Bq, 512, 0, stream>>>(hist, mask, embed, ab2, aow, aob,
                                            weff, qc, aw2t, embf, inter);
        k_final<<<Bq / 8, 256, 0, stream>>>(target, embed, inter, mw1, mb1, mw2,
                                            mb2, ow, ob, out);
    } else if (ws_size >= WEFF_B + QC_B + AW2T_B + INT_B) {
        unsigned short* weff  = (unsigned short*)p;
        float*          qc    = (float*)(p + WEFF_B);
        unsigned short* aw2t  = (unsigned short*)(p + WEFF_B + QC_B);
        float*          inter = (float*)(p + WEFF_B + QC_B + AW2T_B);
        k_weff<<<Bq / BPB, 256, 0, stream>>>(target, embed, aw1, ab1, aw2, weff, qc, aw2t, nullptr);
        k_attn_fast<<<Bq, 512, 0, stream>>>(hist, mask, embed, ab2, aow, aob,
                                            weff, qc, aw2t, nullptr, inter);
        k_final<<<Bq / 8, 256, 0, stream>>>(target, embed, inter, mw1, mb1, mw2,
                                            mb2, ow, ob, out);
    } else {
        float* inter = (float*)p;                    // 1 MB
        k_attn_fb<<<Bq, 256, 0, stream>>>(target, hist, mask, embed, aw1, ab1,
                                          aw2, ab2, aow, aob, inter);
        k_final<<<Bq / 8, 256, 0, stream>>>(target, embed, inter, mw1, mb1, mw2,
                                            mb2, ow, ob, out);
    }
}

// Round 8
// 105.442 us; speedup vs baseline: 1.9311x; 1.9311x over previous
//
#include <hip/hip_runtime.h>
#include <stdint.h>

#define Bq 4096
#define Tq 200
#define TP 208      // padded to 13 tiles of 16
#define NMT 13
#define Vq 100000
#define BPB 8       // b's per k_weff block

typedef __attribute__((ext_vector_type(8))) short short8;   // 8 bf16 in 4 VGPRs
typedef __attribute__((ext_vector_type(4))) float f32x4;
typedef __attribute__((ext_vector_type(4))) unsigned short bfx4;
typedef __attribute__((ext_vector_type(4))) unsigned int u32x4;

static __device__ __forceinline__ unsigned short f2b(float f) {
    unsigned int u = __builtin_bit_cast(unsigned int, f);
    u = u + 0x7fffu + ((u >> 16) & 1u);            // RNE
    return (unsigned short)(u >> 16);
}
static __device__ __forceinline__ float b2f(unsigned short s) {
    unsigned int u = ((unsigned int)s) << 16;
    return __builtin_bit_cast(float, u);
}
// 2x f32 -> packed bf16 (RNE): low16 = lo, high16 = hi
static __device__ __forceinline__ unsigned int pack2(float lo, float hi) {
    unsigned int r;
    asm volatile("v_cvt_pk_bf16_f32 %0, %1, %2" : "=v"(r) : "v"(lo), "v"(hi));
    return r;
}

// swizzled [R][64]-bf16 tile helpers: byte = (row*128 + col*2) ^ ((row&7)<<4)
static __device__ __forceinline__ short8 ld8sw(const unsigned short* base, int row, int col8) {
    return *(const short8*)((const char*)base + (((row << 7) + (col8 << 1)) ^ ((row & 7) << 4)));
}
static __device__ __forceinline__ void st16sw(unsigned short* base, int row, int col, unsigned short v) {
    *(unsigned short*)((char*)base + (((row << 7) + (col << 1)) ^ ((row & 7) << 4))) = v;
}
static __device__ __forceinline__ void st64sw(unsigned short* base, int row, int col4, bfx4 v) {
    *(bfx4*)((char*)base + (((row << 7) + (col4 << 3)) ^ ((row & 7) << 4))) = v;
}
static __device__ __forceinline__ void st128sw(unsigned short* base, int row, int col8, short8 v) {
    *(short8*)((char*)base + (((row << 7) + (col8 << 1)) ^ ((row & 7) << 4))) = v;
}

// ---------------- K0: per-b effective weights (+ bf16 embed table append) ----------------
extern "C" __global__ __launch_bounds__(256) void k_weff(
    const int* __restrict__ target, const float* __restrict__ embed,
    const float* __restrict__ aw1, const float* __restrict__ ab1,
    const float* __restrict__ aw2,
    unsigned short* __restrict__ weff_all, float* __restrict__ qc_all,
    unsigned short* __restrict__ aw2t, unsigned short* __restrict__ embf)
{
    __shared__ float s_C[64][64];    // [i][j]
    __shared__ float s_W3[64][64];   // [i][j]
    __shared__ float s_W12T[64][64]; // [j][i]
    __shared__ float s_qb[BPB][64];
    int tid = threadIdx.x;
    int b0 = blockIdx.x * BPB;

    for (int idx = tid; idx < 4096; idx += 256) {
        int i = idx >> 6, j = idx & 63;
        float a0 = aw1[i * 64 + j];
        float a1 = aw1[(64 + i) * 64 + j];
        float a2 = aw1[(128 + i) * 64 + j];
        float a3 = aw1[(192 + i) * 64 + j];
        s_C[i][j] = a0 + a2;
        s_W3[i][j] = a3;
        s_W12T[j][i] = a1 - a2;
    }
    for (int idx = tid; idx < BPB * 64; idx += 256) {
        int bb = idx >> 6, j = idx & 63;
        s_qb[bb][j] = embed[(long)target[b0 + bb] * 64 + j];
    }
    if (blockIdx.x == 0) {
        for (int idx = tid; idx < 2048; idx += 256) {
            int j = idx >> 5, k = idx & 31;
            aw2t[k * 64 + j] = f2b(aw2[j * 32 + k]);
        }
    }
    __syncthreads();

    // qc
    for (int p = tid; p < BPB * 64; p += 256) {
        int bb = p >> 6, j = p & 63;
        float acc = ab1[j];
        #pragma unroll
        for (int i4 = 0; i4 < 64; i4 += 4) {
            f32x4 qv = *(const f32x4*)&s_qb[bb][i4];
            f32x4 wv = *(const f32x4*)&s_W12T[j][i4];
            acc += qv.x * wv.x + qv.y * wv.y + qv.z * wv.z + qv.w * wv.w;
        }
        qc_all[(long)(b0 + bb) * 64 + j] = acc;
    }
    // weff: thread owns (j = tid>>2, i0 = (tid&3)*16)
    int jw = tid >> 2, i0 = (tid & 3) << 4;
    for (int bb = 0; bb < BPB; ++bb) {
        unsigned int pk[8];
        #pragma unroll
        for (int u = 0; u < 8; ++u) {
            int i = i0 + u * 2;
            float w0 = s_C[i][jw] + s_qb[bb][i] * s_W3[i][jw];
            float w1 = s_C[i + 1][jw] + s_qb[bb][i + 1] * s_W3[i + 1][jw];
            pk[u] = pack2(w0, w1);
        }
        u32x4* dst = (u32x4*)(weff_all + (((long)(b0 + bb)) << 12) + jw * 64 + i0);
        u32x4 v0 = { pk[0], pk[1], pk[2], pk[3] };
        u32x4 v1 = { pk[4], pk[5], pk[6], pk[7] };
        dst[0] = v0;
        dst[1] = v1;
    }
    // bf16 embed table (grid-stride append)
    if (embf) {
        long gsz = (long)gridDim.x * 256;
        for (long i = (long)blockIdx.x * 256 + tid; i < (long)Vq * 8; i += gsz) {
            const float* src = embed + i * 8;
            f32x4 e0 = *(const f32x4*)src;
            f32x4 e1 = *(const f32x4*)(src + 4);
            u32x4 pk = { pack2(e0.x, e0.y), pack2(e0.z, e0.w),
                         pack2(e1.x, e1.y), pack2(e1.z, e1.w) };
            *(u32x4*)(embf + i * 8) = pk;
        }
    }
}

// ---------------- KA fast: fused attention -> interest[b][64], 256 thr, LDS-lean ----------------
extern "C" __global__ __launch_bounds__(256, 4) void k_attn_fast(
    const int* __restrict__ hist, const int* __restrict__ mask,
    const float* __restrict__ embed,
    const float* __restrict__ ab2, const float* __restrict__ aow,
    const float* __restrict__ aob,
    const unsigned short* __restrict__ weff_all,
    const float* __restrict__ qc_all,
    const unsigned short* __restrict__ aw2t,
    const unsigned short* __restrict__ embf,
    float* __restrict__ inter64)
{
    __shared__ int s_id[TP];
    __shared__ alignas(16) unsigned short s_hist[TP * 64];   // bf16, swizzled
    __shared__ float s_sc[TP];
    __shared__ float s_red[8];
    __shared__ float s_intp[4][64];

    int tid = threadIdx.x;
    int lane = tid & 63;
    int wv = tid >> 6;
    int b = blockIdx.x;
    int r16 = lane & 15;
    int kg = lane >> 4;

    // prologue loads (no LDS dependency -> latency hidden)
    // wf = A-fragment of Weff^T (M=j), af = A-fragment of aw2^T (M=kk) — same data as unswapped!
    short8 wf[4][2];
    #pragma unroll
    for (int n = 0; n < 4; ++n)
        #pragma unroll
        for (int h = 0; h < 2; ++h)
            wf[n][h] = *(const short8*)(weff_all + (((long)b) << 12) + (n * 16 + r16) * 64 + h * 32 + kg * 8);
    short8 af[2][2];
    #pragma unroll
    for (int n = 0; n < 2; ++n)
        #pragma unroll
        for (int h = 0; h < 2; ++h)
            af[n][h] = *(const short8*)(aw2t + (n * 16 + r16) * 64 + h * 32 + kg * 8);
    // swapped D layout: row j = n*16 + kg*4 + r -> contiguous f32x4 C-init per n
    f32x4 qcv[4];
    #pragma unroll
    for (int n = 0; n < 4; ++n)
        qcv[n] = *(const f32x4*)&qc_all[(long)b * 64 + n * 16 + kg * 4];
    f32x4 ab2v[2], aowv[2];
    #pragma unroll
    for (int n = 0; n < 2; ++n) {
        ab2v[n] = *(const f32x4*)&ab2[n * 16 + kg * 4];
        aowv[n] = *(const f32x4*)&aow[n * 16 + kg * 4];
    }
    float aob0 = aob[0];

    for (int t = tid; t < TP; t += 256) s_id[t] = hist[b * Tq + ((t < Tq) ? t : 0)];
    __syncthreads();

    // stage hist rows as bf16
    if (embf) {
        for (int u = tid; u < TP * 8; u += 256) {
            int t = u >> 3, c = u & 7;
            short8 v = *(const short8*)(embf + (long)s_id[t] * 64 + c * 8);
            st128sw(s_hist, t, c * 8, v);
        }
    } else {
        for (int u = tid; u < TP * 8; u += 256) {
            int t = u >> 3, c = u & 7;
            const float* src = &embed[(long)s_id[t] * 64 + c * 8];
            f32x4 e0 = *(const f32x4*)src;
            f32x4 e1 = *(const f32x4*)(src + 4);
            u32x4 pk = { pack2(e0.x, e0.y), pack2(e0.z, e0.w),
                         pack2(e1.x, e1.y), pack2(e1.z, e1.w) };
            *(u32x4*)((char*)s_hist + (((t << 7) + (c << 4)) ^ ((t & 7) << 4))) = pk;
        }
    }
    __syncthreads();

    int srcA = r16 + (((kg << 1) & 3) << 4);
    int srcB = srcA + 16;

    // scores: per-wave private M-tiles (over t), fully in-register h1 path
    for (int m = wv; m < NMT; m += 4) {
        int row0 = m * 16;
        // B-fragment = hist^T (col t = r16, k = embed dim) — same loads as before
        short8 a0 = ld8sw(s_hist, row0 + r16, kg * 8);
        short8 a1 = ld8sw(s_hist, row0 + r16, 32 + kg * 8);
        // GEMM1 swapped: h1^T[j][t] ; lane holds t=r16, j = n*16+kg*4+r
        f32x4 d[4];
        #pragma unroll
        for (int n = 0; n < 4; ++n) {
            f32x4 z = qcv[n];
            z = __builtin_amdgcn_mfma_f32_16x16x32_bf16(wf[n][0], a0, z, 0, 0, 0);
            z = __builtin_amdgcn_mfma_f32_16x16x32_bf16(wf[n][1], a1, z, 0, 0, 0);
            d[n] = z;
        }
        // relu + pack: p0[n]=bf16(r0,r1), p1[n]=bf16(r2,r3)
        unsigned int p0[4], p1[4];
        #pragma unroll
        for (int n = 0; n < 4; ++n) {
            p0[n] = pack2(fmaxf(d[n][0], 0.f), fmaxf(d[n][1], 0.f));
            p1[n] = pack2(fmaxf(d[n][2], 0.f), fmaxf(d[n][3], 0.f));
        }
        // in-register repack to GEMM2 B-fragment: target lane kg needs j = kg*8..+7 (b0), 32+kg*8..+7 (b1)
        // j = 16n + 4kg_s + r ; source lanes kg_s = (2kg)&3 (srcA) and +1 (srcB); n = kg>>1 (+2 for b1)
        u32x4 w0, w1;
        {
            unsigned int xA0 = __shfl(p0[0], srcA), xA1 = __shfl(p0[1], srcA);
            unsigned int yA0 = __shfl(p1[0], srcA), yA1 = __shfl(p1[1], srcA);
            unsigned int xB0 = __shfl(p0[0], srcB), xB1 = __shfl(p0[1], srcB);
            unsigned int yB0 = __shfl(p1[0], srcB), yB1 = __shfl(p1[1], srcB);
            w0.x = (kg < 2) ? xA0 : xA1;
            w0.y = (kg < 2) ? yA0 : yA1;
            w0.z = (kg < 2) ? xB0 : xB1;
            w0.w = (kg < 2) ? yB0 : yB1;
            unsigned int uA0 = __shfl(p0[2], srcA), uA1 = __shfl(p0[3], srcA);
            unsigned int vA0 = __shfl(p1[2], srcA), vA1 = __shfl(p1[3], srcA);
            unsigned int uB0 = __shfl(p0[2], srcB), uB1 = __shfl(p0[3], srcB);
            unsigned int vB0 = __shfl(p1[2], srcB), vB1 = __shfl(p1[3], srcB);
            w1.x = (kg < 2) ? uA0 : uA1;
            w1.y = (kg < 2) ? vA0 : vA1;
            w1.z = (kg < 2) ? uB0 : uB1;
            w1.w = (kg < 2) ? vB0 : vB1;
        }
        short8 bh0 = __builtin_bit_cast(short8, w0);
        short8 bh1 = __builtin_bit_cast(short8, w1);
        // GEMM2 swapped: h2^T[kk][t]; lane holds t=r16, kk = n2*16+kg*4+r
        f32x4 e[2];
        #pragma unroll
        for (int n = 0; n < 2; ++n) {
            f32x4 z = { 0.f, 0.f, 0.f, 0.f };
            z = __builtin_amdgcn_mfma_f32_16x16x32_bf16(af[n][0], bh0, z, 0, 0, 0);
            z = __builtin_amdgcn_mfma_f32_16x16x32_bf16(af[n][1], bh1, z, 0, 0, 0);
            e[n] = z;
        }
        // layer3: per-lane partial over its 8 kk, then reduce across kg groups
        float sacc = 0.f;
        #pragma unroll
        for (int n = 0; n < 2; ++n)
            #pragma unroll
            for (int r = 0; r < 4; ++r)
                sacc += fmaxf(e[n][r] + ab2v[n][r], 0.f) * aowv[n][r];
        sacc += __shfl_xor(sacc, 16);
        sacc += __shfl_xor(sacc, 32);
        if (kg == 0) s_sc[row0 + r16] = sacc + aob0;
    }
    __syncthreads();

    // softmax over t<200 (masked; mask is int32)
    float sc = -1e30f;
    if (tid < Tq) {
        int mk = mask[(long)b * Tq + tid];
        sc = mk ? s_sc[tid] : -1e9f;
    }
    float mx = sc;
    #pragma unroll
    for (int off = 1; off < 64; off <<= 1) mx = fmaxf(mx, __shfl_xor(mx, off));
    if (lane == 0) s_red[wv] = mx;
    __syncthreads();
    mx = fmaxf(fmaxf(s_red[0], s_red[1]), fmaxf(s_red[2], s_red[3]));
    float ex = (tid < Tq) ? expf(sc - mx) : 0.f;
    float sm = ex;
    #pragma unroll
    for (int off = 1; off < 64; off <<= 1) sm += __shfl_xor(sm, off);
    if (lane == 0) s_red[4 + wv] = sm;
    __syncthreads();
    float tot = s_red[4] + s_red[5] + s_red[6] + s_red[7];
    if (tid < Tq) s_sc[tid] = ex / tot;
    else if (tid < TP) s_sc[tid] = 0.f;
    __syncthreads();

    // interest: 8 rows x 8 col-groups per wave-op, wide conflict-free LDS reads
    int cg = lane & 7;   // cols cg*8..+7
    int tg = lane >> 3;  // row within 8-row group
    float acc8[8];
    #pragma unroll
    for (int u = 0; u < 8; ++u) acc8[u] = 0.f;
    for (int t = wv * 8 + tg; t < TP; t += 32) {
        float w = s_sc[t];
        short8 h = ld8sw(s_hist, t, cg * 8);
        #pragma unroll
        for (int u = 0; u < 8; ++u) acc8[u] += w * b2f((unsigned short)h[u]);
    }
    #pragma unroll
    for (int u = 0; u < 8; ++u) {
        acc8[u] += __shfl_xor(acc8[u], 8);
        acc8[u] += __shfl_xor(acc8[u], 16);
        acc8[u] += __shfl_xor(acc8[u], 32);
    }
    if (tg == 0) {
        #pragma unroll
        for (int u = 0; u < 8; ++u) s_intp[wv][cg * 8 + u] = acc8[u];
    }
    __syncthreads();
    if (tid < 64)
        inter64[(long)b * 64 + tid] = s_intp[0][tid] + s_intp[1][tid] + s_intp[2][tid] + s_intp[3][tid];
}

// ---------------- KA fallback (round-5 proven path, used if ws too small) ----------------
extern "C" __global__ __launch_bounds__(256, 3) void k_attn_fb(
    const int* __restrict__ target, const int* __restrict__ hist,
    const int* __restrict__ mask,
    const float* __restrict__ embed, const float* __restrict__ aw1,
    const float* __restrict__ ab1, const float* __restrict__ aw2,
    const float* __restrict__ ab2, const float* __restrict__ aow,
    const float* __restrict__ aob,
    float* __restrict__ inter64)
{
    __shared__ int s_id[TP];
    __shared__ float s_q[64];
    __shared__ float s_qc[64];
    __shared__ float s_qcp[4][64];
    __shared__ alignas(16) unsigned short s_hist[TP * 64];
    __shared__ alignas(16) unsigned short s_WeffT[64 * 64];
    __shared__ alignas(16) unsigned short s_aw2T[32 * 64];
    __shared__ alignas(16) unsigned short s_h1[4 * 16 * 64];
    __shared__ float s_sc[TP];
    __shared__ float s_aow[32];
    __shared__ float s_ab2[32];
    __shared__ float s_red[8];
    __shared__ float s_intp[4][64];

    int tid = threadIdx.x;
    int lane = tid & 63;
    int wv = tid >> 6;
    int b = blockIdx.x;

    int tgt = target[b];
    if (tid < 64) s_q[tid] = embed[(long)tgt * 64 + tid];
    for (int t = tid; t < TP; t += 256) s_id[t] = hist[b * Tq + ((t < Tq) ? t : 0)];
    if (tid < 32) { s_aow[tid] = aow[tid]; s_ab2[tid] = ab2[tid]; }
    __syncthreads();

    for (int idx = tid; idx < 4096; idx += 256) {
        int i = idx >> 6, j = idx & 63;
        float w = aw1[i * 64 + j] + aw1[(128 + i) * 64 + j] + s_q[i] * aw1[(192 + i) * 64 + j];
        st16sw(s_WeffT, j, i, f2b(w));
    }
    for (int idx = tid; idx < 2048; idx += 256) {
        int j = idx >> 5, k = idx & 31;
        st16sw(s_aw2T, k, j, f2b(aw2[j * 32 + k]));
    }
    {
        float acc = 0.f;
        #pragma unroll
        for (int ii = 0; ii < 16; ++ii) {
            int i = wv * 16 + ii;
            acc += s_q[i] * (aw1[(64 + i) * 64 + lane] - aw1[(128 + i) * 64 + lane]);
        }
        s_qcp[wv][lane] = acc;
    }
    for (int u = tid; u < TP * 16; u += 256) {
        int t = u >> 4, j4 = u & 15;
        f32x4 e = *(const f32x4*)&embed[(long)s_id[t] * 64 + j4 * 4];
        bfx4 p = { f2b(e.x), f2b(e.y), f2b(e.z), f2b(e.w) };
        st64sw(s_hist, t, j4, p);
    }
    __syncthreads();
    if (tid < 64) s_qc[tid] = ab1[tid] + s_qcp[0][tid] + s_qcp[1][tid] + s_qcp[2][tid] + s_qcp[3][tid];
    __syncthreads();

    int r16 = lane & 15;
    int kg = lane >> 4;
    float aob0 = aob[0];
    unsigned short* h1w = s_h1 + wv * 16 * 64;

    for (int m = wv; m < NMT; m += 4) {
        int row0 = m * 16;
        short8 a0 = ld8sw(s_hist, row0 + r16, kg * 8);
        short8 a1 = ld8sw(s_hist, row0 + r16, 32 + kg * 8);
        f32x4 d[4];
        #pragma unroll
        for (int n = 0; n < 4; ++n) {
            short8 b0 = ld8sw(s_WeffT, n * 16 + r16, kg * 8);
            short8 b1 = ld8sw(s_WeffT, n * 16 + r16, 32 + kg * 8);
            float qcv = s_qc[n * 16 + r16];
            f32x4 z = { qcv, qcv, qcv, qcv };
            z = __builtin_amdgcn_mfma_f32_16x16x32_bf16(a0, b0, z, 0, 0, 0);
            z = __builtin_amdgcn_mfma_f32_16x16x32_bf16(a1, b1, z, 0, 0, 0);
            d[n] = z;
        }
        #pragma unroll
        for (int n = 0; n < 4; ++n) {
            int col = n * 16 + r16;
            #pragma unroll
            for (int r = 0; r < 4; ++r)
                st16sw(h1w, kg * 4 + r, col, f2b(fmaxf(d[n][r], 0.f)));
        }
        short8 ha0 = ld8sw(h1w, r16, kg * 8);
        short8 ha1 = ld8sw(h1w, r16, 32 + kg * 8);
        f32x4 e[2];
        #pragma unroll
        for (int n = 0; n < 2; ++n) {
            short8 b0 = ld8sw(s_aw2T, n * 16 + r16, kg * 8);
            short8 b1 = ld8sw(s_aw2T, n * 16 + r16, 32 + kg * 8);
            f32x4 z = { 0.f, 0.f, 0.f, 0.f };
            z = __builtin_amdgcn_mfma_f32_16x16x32_bf16(ha0, b0, z, 0, 0, 0);
            z = __builtin_amdgcn_mfma_f32_16x16x32_bf16(ha1, b1, z, 0, 0, 0);
            e[n] = z;
        }
        #pragma unroll
        for (int r = 0; r < 4; ++r) {
            float h20 = fmaxf(e[0][r] + s_ab2[r16], 0.f);
            float h21 = fmaxf(e[1][r] + s_ab2[16 + r16], 0.f);
            float p = h20 * s_aow[r16] + h21 * s_aow[16 + r16];
            p += __shfl_xor(p, 1);
            p += __shfl_xor(p, 2);
            p += __shfl_xor(p, 4);
            p += __shfl_xor(p, 8);
            if (r16 == 0) s_sc[row0 + kg * 4 + r] = p + aob0;
        }
    }
    __syncthreads();

    float sc = -1e30f;
    if (tid < Tq) {
        int mk = mask[(long)b * Tq + tid];
        sc = mk ? s_sc[tid] : -1e9f;
    }
    float mx = sc;
    #pragma unroll
    for (int off = 1; off < 64; off <<= 1) mx = fmaxf(mx, __shfl_xor(mx, off));
    if (lane == 0) s_red[wv] = mx;
    __syncthreads();
    mx = fmaxf(fmaxf(s_red[0], s_red[1]), fmaxf(s_red[2], s_red[3]));
    float ex = (tid < Tq) ? expf(sc - mx) : 0.f;
    float sm = ex;
    #pragma unroll
    for (int off = 1; off < 64; off <<= 1) sm += __shfl_xor(sm, off);
    if (lane == 0) s_red[4 + wv] = sm;
    __syncthreads();
    float tot = s_red[4] + s_red[5] + s_red[6] + s_red[7];
    if (tid < Tq) s_sc[tid] = ex / tot;
    __syncthreads();

    float acc = 0.f;
    for (int t = wv; t < Tq; t += 4)
        acc += s_sc[t] * b2f(*(const unsigned short*)((const char*)s_hist +
                 (((t << 7) + (lane << 1)) ^ ((t & 7) << 4))));
    s_intp[wv][lane] = acc;
    __syncthreads();
    if (tid < 64)
        inter64[(long)b * 64 + tid] = s_intp[0][tid] + s_intp[1][tid] + s_intp[2][tid] + s_intp[3][tid];
}

// ---------------- KB: final MLP [q | interest] 128->256->128->1, fp32, 8 rows/block ----------------
extern "C" __global__ __launch_bounds__(256) void k_final(
    const int* __restrict__ target, const float* __restrict__ embed,
    const float* __restrict__ inter64, const float* __restrict__ mw1,
    const float* __restrict__ mb1, const float* __restrict__ mw2,
    const float* __restrict__ mb2, const float* __restrict__ ow,
    const float* __restrict__ ob, float* __restrict__ out)
{
    __shared__ alignas(16) float s_in[8][128];
    __shared__ alignas(16) float s_g1[8][256];
    __shared__ alignas(16) float s_g2[8][128];
    int tid = threadIdx.x;
    long b0 = (long)blockIdx.x * 8;
    for (int idx = tid; idx < 1024; idx += 256) {
        int r = idx >> 7, c = idx & 127;
        s_in[r][c] = (c < 64) ? embed[(long)target[b0 + r] * 64 + c]
                              : inter64[(b0 + r) * 64 + (c - 64)];
    }
    __syncthreads();
    {
        float acc[8];
        float bias = mb1[tid];
        #pragma unroll
        for (int r = 0; r < 8; ++r) acc[r] = bias;
        for (int i0 = 0; i0 < 128; i0 += 4) {
            float w0 = mw1[(i0 + 0) * 256 + tid];
            float w1 = mw1[(i0 + 1) * 256 + tid];
            float w2 = mw1[(i0 + 2) * 256 + tid];
            float w3 = mw1[(i0 + 3) * 256 + tid];
            #pragma unroll
            for (int r = 0; r < 8; ++r) {
                f32x4 e = *(const f32x4*)&s_in[r][i0];
                acc[r] += e.x * w0 + e.y * w1 + e.z * w2 + e.w * w3;
            }
        }
        #pragma unroll
        for (int r = 0; r < 8; ++r) s_g1[r][tid] = fmaxf(acc[r], 0.f);
    }
    __syncthreads();
    {
        int o = tid & 127, rh = tid >> 7;
        float acc[4];
        float bias = mb2[o];
        #pragma unroll
        for (int r = 0; r < 4; ++r) acc[r] = bias;
        for (int i0 = 0; i0 < 256; i0 += 4) {
            float w0 = mw2[(i0 + 0) * 128 + o];
            float w1 = mw2[(i0 + 1) * 128 + o];
            float w2 = mw2[(i0 + 2) * 128 + o];
            float w3 = mw2[(i0 + 3) * 128 + o];
            #pragma unroll
            for (int r = 0; r < 4; ++r) {
                f32x4 e = *(const f32x4*)&s_g1[rh * 4 + r][i0];
                acc[r] += e.x * w0 + e.y * w1 + e.z * w2 + e.w * w3;
            }
        }
        #pragma unroll
        for (int r = 0; r < 4; ++r) s_g2[rh * 4 + r][o] = fmaxf(acc[r], 0.f);
    }
    __syncthreads();
    {
        int r = tid >> 5, l32 = tid & 31;
        float acc = 0.f;
        #pragma unroll
        for (int k = 0; k < 4; ++k) acc += s_g2[r][l32 + k * 32] * ow[l32 + k * 32];
        acc += __shfl_xor(acc, 1);
        acc += __shfl_xor(acc, 2);
        acc += __shfl_xor(acc, 4);
        acc += __shfl_xor(acc, 8);
        acc += __shfl_xor(acc, 16);
        if (l32 == 0) out[b0 + r] = acc + ob[0];
    }
}

extern "C" void kernel_launch(void* const* d_in, const int* in_sizes, int n_in,
                              void* d_out, int out_size, void* d_ws, size_t ws_size,
                              hipStream_t stream)
{
    const int*   target = (const int*)d_in[0];
    const int*   hist   = (const int*)d_in[1];
    const int*   mask   = (const int*)d_in[2];
    const float* embed  = (const float*)d_in[3];
    const float* aw1    = (const float*)d_in[4];
    const float* ab1    = (const float*)d_in[5];
    const float* aw2    = (const float*)d_in[6];
    const float* ab2    = (const float*)d_in[7];
    const float* aow    = (const float*)d_in[8];
    const float* aob    = (const float*)d_in[9];
    const float* mw1    = (const float*)d_in[10];
    const float* mb1    = (const float*)d_in[11];
    const float* mw2    = (const float*)d_in[12];
    const float* mb2    = (const float*)d_in[13];
    const float* ow     = (const float*)d_in[14];
    const float* ob     = (const float*)d_in[15];
    float* out = (float*)d_out;

    const size_t WEFF_B = (size_t)Bq * 4096 * 2;     // 32 MB
    const size_t QC_B   = (size_t)Bq * 64 * 4;       // 1 MB
    const size_t AW2T_B = 4096;                      // 4 KB
    const size_t EMBF_B = (size_t)Vq * 64 * 2;       // 12.8 MB
    const size_t INT_B  = (size_t)Bq * 64 * 4;       // 1 MB
    char* p = (char*)d_ws;

    if (ws_size >= WEFF_B + QC_B + AW2T_B + EMBF_B + INT_B) {
        unsigned short* weff  = (unsigned short*)p;
        float*          qc    = (float*)(p + WEFF_B);
        unsigned short* aw2t  = (unsigned short*)(p + WEFF_B + QC_B);
        unsigned short* embf  = (unsigned short*)(p + WEFF_B + QC_B + AW2T_B);
        float*          inter = (float*)(p + WEFF_B + QC_B + AW2T_B + EMBF_B);
        k_weff<<<Bq / BPB, 256, 0, stream>>>(target, embed, aw1, ab1, aw2, weff, qc, aw2t, embf);
        k_attn_fast<<<Bq, 256, 0, stream>>>(hist, mask, embed, ab2, aow, aob,
                                            weff, qc, aw2t, embf, inter);
        k_final<<<Bq / 8, 256, 0, stream>>>(target, embed, inter, mw1, mb1, mw2,
                                            mb2, ow, ob, out);
    } else if (ws_size >= WEFF_B + QC_B + AW2T_B + INT_B) {
        unsigned short* weff  = (unsigned short*)p;
        float*          qc    = (float*)(p + WEFF_B);
        unsigned short* aw2t  = (unsigned short*)(p + WEFF_B + QC_B);
        float*          inter = (float*)(p + WEFF_B + QC_B + AW2T_B);
        k_weff<<<Bq / BPB, 256, 0, stream>>>(target, embed, aw1, ab1, aw2, weff, qc, aw2t, nullptr);
        k_attn_fast<<<Bq, 256, 0, stream>>>(hist, mask, embed, ab2, aow, aob,
                                            weff, qc, aw2t, nullptr, inter);
        k_final<<<Bq / 8, 256, 0, stream>>>(target, embed, inter, mw1, mb1, mw2,
                                            mb2, ow, ob, out);
    } else {
        float* inter = (float*)p;                    // 1 MB
        k_attn_fb<<<Bq, 256, 0, stream>>>(target, hist, mask, embed, aw1, ab1,
                                          aw2, ab2, aow, aob, inter);
        k_final<<<Bq / 8, 256, 0, stream>>>(target, embed, inter, mw1, mb1, mw2,
                                            mb2, ow, ob, out);
    }
}

// Round 9
// 92.163 us; speedup vs baseline: 2.2093x; 1.1441x over previous
//
#include <hip/hip_runtime.h>
#include <stdint.h>

#define Bq 4096
#define Tq 200
#define TP 208      // padded to 13 tiles of 16
#define NMT 13
#define Vq 100000
#define BPB 8       // b's per k_weff block

typedef __attribute__((ext_vector_type(8))) short short8;   // 8 bf16 in 4 VGPRs
typedef __attribute__((ext_vector_type(4))) float f32x4;
typedef __attribute__((ext_vector_type(4))) unsigned short bfx4;
typedef __attribute__((ext_vector_type(4))) unsigned int u32x4;

static __device__ __forceinline__ unsigned short f2b(float f) {
    unsigned int u = __builtin_bit_cast(unsigned int, f);
    u = u + 0x7fffu + ((u >> 16) & 1u);            // RNE
    return (unsigned short)(u >> 16);
}
static __device__ __forceinline__ float b2f(unsigned short s) {
    unsigned int u = ((unsigned int)s) << 16;
    return __builtin_bit_cast(float, u);
}
// 2x f32 -> packed bf16 (RNE): low16 = lo, high16 = hi
static __device__ __forceinline__ unsigned int pack2(float lo, float hi) {
    unsigned int r;
    asm volatile("v_cvt_pk_bf16_f32 %0, %1, %2" : "=v"(r) : "v"(lo), "v"(hi));
    return r;
}

// swizzled [R][64]-bf16 tile helpers: byte = (row*128 + col*2) ^ ((row&7)<<4)
static __device__ __forceinline__ short8 ld8sw(const unsigned short* base, int row, int col8) {
    return *(const short8*)((const char*)base + (((row << 7) + (col8 << 1)) ^ ((row & 7) << 4)));
}
static __device__ __forceinline__ void st16sw(unsigned short* base, int row, int col, unsigned short v) {
    *(unsigned short*)((char*)base + (((row << 7) + (col << 1)) ^ ((row & 7) << 4))) = v;
}
static __device__ __forceinline__ void st64sw(unsigned short* base, int row, int col4, bfx4 v) {
    *(bfx4*)((char*)base + (((row << 7) + (col4 << 3)) ^ ((row & 7) << 4))) = v;
}
static __device__ __forceinline__ void st128sw(unsigned short* base, int row, int col8, short8 v) {
    *(short8*)((char*)base + (((row << 7) + (col8 << 1)) ^ ((row & 7) << 4))) = v;
}

// ---------------- K0: per-b effective weights (+ bf16 embed table append) ----------------
extern "C" __global__ __launch_bounds__(256) void k_weff(
    const int* __restrict__ target, const float* __restrict__ embed,
    const float* __restrict__ aw1, const float* __restrict__ ab1,
    const float* __restrict__ aw2,
    unsigned short* __restrict__ weff_all, float* __restrict__ qc_all,
    unsigned short* __restrict__ aw2t, unsigned short* __restrict__ embf)
{
    __shared__ float s_C[64][64];     // [i][j]
    __shared__ float s_W3[64][64];    // [i][j]
    __shared__ float s_W12T[64][65];  // [j][i], padded: write bank = j+i (conflict-free)
    __shared__ float s_qb[BPB][64];
    int tid = threadIdx.x;
    int b0 = blockIdx.x * BPB;

    for (int idx = tid; idx < 4096; idx += 256) {
        int i = idx >> 6, j = idx & 63;
        float a0 = aw1[i * 64 + j];
        float a1 = aw1[(64 + i) * 64 + j];
        float a2 = aw1[(128 + i) * 64 + j];
        float a3 = aw1[(192 + i) * 64 + j];
        s_C[i][j] = a0 + a2;
        s_W3[i][j] = a3;
        s_W12T[j][i] = a1 - a2;
    }
    for (int idx = tid; idx < BPB * 64; idx += 256) {
        int bb = idx >> 6, j = idx & 63;
        s_qb[bb][j] = embed[(long)target[b0 + bb] * 64 + j];
    }
    if (blockIdx.x == 0) {
        for (int idx = tid; idx < 2048; idx += 256) {
            int j = idx >> 5, k = idx & 31;
            aw2t[k * 64 + j] = f2b(aw2[j * 32 + k]);
        }
    }
    __syncthreads();

    // qc (scalar LDS reads; row stride 65 -> conflict-free)
    for (int p = tid; p < BPB * 64; p += 256) {
        int bb = p >> 6, j = p & 63;
        float acc = ab1[j];
        #pragma unroll 8
        for (int i = 0; i < 64; ++i)
            acc += s_qb[bb][i] * s_W12T[j][i];
        qc_all[(long)(b0 + bb) * 64 + j] = acc;
    }
    // weff: thread owns (j = tid>>2, i0 = (tid&3)*16)
    int jw = tid >> 2, i0 = (tid & 3) << 4;
    for (int bb = 0; bb < BPB; ++bb) {
        unsigned int pk[8];
        #pragma unroll
        for (int u = 0; u < 8; ++u) {
            int i = i0 + u * 2;
            float w0 = s_C[i][jw] + s_qb[bb][i] * s_W3[i][jw];
            float w1 = s_C[i + 1][jw] + s_qb[bb][i + 1] * s_W3[i + 1][jw];
            pk[u] = pack2(w0, w1);
        }
        u32x4* dst = (u32x4*)(weff_all + (((long)(b0 + bb)) << 12) + jw * 64 + i0);
        u32x4 v0 = { pk[0], pk[1], pk[2], pk[3] };
        u32x4 v1 = { pk[4], pk[5], pk[6], pk[7] };
        dst[0] = v0;
        dst[1] = v1;
    }
    // bf16 embed table (grid-stride append)
    if (embf) {
        long gsz = (long)gridDim.x * 256;
        for (long i = (long)blockIdx.x * 256 + tid; i < (long)Vq * 8; i += gsz) {
            const float* src = embed + i * 8;
            f32x4 e0 = *(const f32x4*)src;
            f32x4 e1 = *(const f32x4*)(src + 4);
            u32x4 pk = { pack2(e0.x, e0.y), pack2(e0.z, e0.w),
                         pack2(e1.x, e1.y), pack2(e1.z, e1.w) };
            *(u32x4*)(embf + i * 8) = pk;
        }
    }
}

// ---------------- KA fast: fused attention -> interest[b][64], 256 thr, LDS-lean ----------------
extern "C" __global__ __launch_bounds__(256, 4) void k_attn_fast(
    const int* __restrict__ hist, const int* __restrict__ mask,
    const float* __restrict__ embed,
    const float* __restrict__ ab2, const float* __restrict__ aow,
    const float* __restrict__ aob,
    const unsigned short* __restrict__ weff_all,
    const float* __restrict__ qc_all,
    const unsigned short* __restrict__ aw2t,
    const unsigned short* __restrict__ embf,
    float* __restrict__ inter64)
{
    __shared__ alignas(16) unsigned short s_hist[TP * 64];   // bf16, swizzled
    __shared__ float s_sc[TP];
    __shared__ float s_red[8];
    __shared__ float s_intp[4][64];

    int tid = threadIdx.x;
    int lane = tid & 63;
    int wv = tid >> 6;
    int b = blockIdx.x;
    int r16 = lane & 15;
    int kg = lane >> 4;

    // ---- staging: read own hist ids (L1 broadcast), issue ALL gathers, store late (T14) ----
    int tt[7];
    short8 g[7];
    #pragma unroll
    for (int k = 0; k < 7; ++k) {
        int u = tid + k * 256;
        int t = u >> 3;
        if (u < TP * 8) {
            int tc = (t < Tq) ? t : 0;
            int id = hist[b * Tq + tc];
            g[k] = *(const short8*)(embf + (long)id * 64 + (u & 7) * 8);
        }
        tt[k] = t;
    }
    // mask (independent) — issue early
    int mk = (tid < Tq) ? mask[(long)b * Tq + tid] : 0;

    // prologue fragment/constant loads (independent of LDS)
    short8 wf[4][2];
    #pragma unroll
    for (int n = 0; n < 4; ++n)
        #pragma unroll
        for (int h = 0; h < 2; ++h)
            wf[n][h] = *(const short8*)(weff_all + (((long)b) << 12) + (n * 16 + r16) * 64 + h * 32 + kg * 8);
    short8 af[2][2];
    #pragma unroll
    for (int n = 0; n < 2; ++n)
        #pragma unroll
        for (int h = 0; h < 2; ++h)
            af[n][h] = *(const short8*)(aw2t + (n * 16 + r16) * 64 + h * 32 + kg * 8);
    f32x4 qcv[4];
    #pragma unroll
    for (int n = 0; n < 4; ++n)
        qcv[n] = *(const f32x4*)&qc_all[(long)b * 64 + n * 16 + kg * 4];
    f32x4 ab2v[2], aowv[2];
    #pragma unroll
    for (int n = 0; n < 2; ++n) {
        ab2v[n] = *(const f32x4*)&ab2[n * 16 + kg * 4];
        aowv[n] = *(const f32x4*)&aow[n * 16 + kg * 4];
    }
    float aob0 = aob[0];

    // store staged rows
    #pragma unroll
    for (int k = 0; k < 7; ++k) {
        int u = tid + k * 256;
        if (u < TP * 8) st128sw(s_hist, tt[k], (u & 7) * 8, g[k]);
    }
    __syncthreads();

    int srcA = r16 + (((kg << 1) & 3) << 4);
    int srcB = srcA + 16;

    // scores: per-wave private M-tiles (over t), fully in-register h1 path
    for (int m = wv; m < NMT; m += 4) {
        int row0 = m * 16;
        short8 a0 = ld8sw(s_hist, row0 + r16, kg * 8);
        short8 a1 = ld8sw(s_hist, row0 + r16, 32 + kg * 8);
        // GEMM1 swapped: h1^T[j][t] ; lane holds t=r16, j = n*16+kg*4+r
        f32x4 d[4];
        #pragma unroll
        for (int n = 0; n < 4; ++n) {
            f32x4 z = qcv[n];
            z = __builtin_amdgcn_mfma_f32_16x16x32_bf16(wf[n][0], a0, z, 0, 0, 0);
            z = __builtin_amdgcn_mfma_f32_16x16x32_bf16(wf[n][1], a1, z, 0, 0, 0);
            d[n] = z;
        }
        // relu + pack
        unsigned int p0[4], p1[4];
        #pragma unroll
        for (int n = 0; n < 4; ++n) {
            p0[n] = pack2(fmaxf(d[n][0], 0.f), fmaxf(d[n][1], 0.f));
            p1[n] = pack2(fmaxf(d[n][2], 0.f), fmaxf(d[n][3], 0.f));
        }
        // in-register repack to GEMM2 B-fragment
        u32x4 w0, w1;
        {
            unsigned int xA0 = __shfl(p0[0], srcA), xA1 = __shfl(p0[1], srcA);
            unsigned int yA0 = __shfl(p1[0], srcA), yA1 = __shfl(p1[1], srcA);
            unsigned int xB0 = __shfl(p0[0], srcB), xB1 = __shfl(p0[1], srcB);
            unsigned int yB0 = __shfl(p1[0], srcB), yB1 = __shfl(p1[1], srcB);
            w0.x = (kg < 2) ? xA0 : xA1;
            w0.y = (kg < 2) ? yA0 : yA1;
            w0.z = (kg < 2) ? xB0 : xB1;
            w0.w = (kg < 2) ? yB0 : yB1;
            unsigned int uA0 = __shfl(p0[2], srcA), uA1 = __shfl(p0[3], srcA);
            unsigned int vA0 = __shfl(p1[2], srcA), vA1 = __shfl(p1[3], srcA);
            unsigned int uB0 = __shfl(p0[2], srcB), uB1 = __shfl(p0[3], srcB);
            unsigned int vB0 = __shfl(p1[2], srcB), vB1 = __shfl(p1[3], srcB);
            w1.x = (kg < 2) ? uA0 : uA1;
            w1.y = (kg < 2) ? vA0 : vA1;
            w1.z = (kg < 2) ? uB0 : uB1;
            w1.w = (kg < 2) ? vB0 : vB1;
        }
        short8 bh0 = __builtin_bit_cast(short8, w0);
        short8 bh1 = __builtin_bit_cast(short8, w1);
        // GEMM2 swapped: h2^T[kk][t]
        f32x4 e[2];
        #pragma unroll
        for (int n = 0; n < 2; ++n) {
            f32x4 z = { 0.f, 0.f, 0.f, 0.f };
            z = __builtin_amdgcn_mfma_f32_16x16x32_bf16(af[n][0], bh0, z, 0, 0, 0);
            z = __builtin_amdgcn_mfma_f32_16x16x32_bf16(af[n][1], bh1, z, 0, 0, 0);
            e[n] = z;
        }
        // layer3
        float sacc = 0.f;
        #pragma unroll
        for (int n = 0; n < 2; ++n)
            #pragma unroll
            for (int r = 0; r < 4; ++r)
                sacc += fmaxf(e[n][r] + ab2v[n][r], 0.f) * aowv[n][r];
        sacc += __shfl_xor(sacc, 16);
        sacc += __shfl_xor(sacc, 32);
        if (kg == 0) s_sc[row0 + r16] = sacc + aob0;
    }
    __syncthreads();

    // softmax over t<200 (masked; mask is int32, preloaded)
    float sc = (tid < Tq) ? (mk ? s_sc[tid] : -1e9f) : -1e30f;
    float mx = sc;
    #pragma unroll
    for (int off = 1; off < 64; off <<= 1) mx = fmaxf(mx, __shfl_xor(mx, off));
    if (lane == 0) s_red[wv] = mx;
    __syncthreads();
    mx = fmaxf(fmaxf(s_red[0], s_red[1]), fmaxf(s_red[2], s_red[3]));
    float ex = (tid < Tq) ? expf(sc - mx) : 0.f;
    float sm = ex;
    #pragma unroll
    for (int off = 1; off < 64; off <<= 1) sm += __shfl_xor(sm, off);
    if (lane == 0) s_red[4 + wv] = sm;
    __syncthreads();
    float tot = s_red[4] + s_red[5] + s_red[6] + s_red[7];
    if (tid < Tq) s_sc[tid] = ex / tot;
    else if (tid < TP) s_sc[tid] = 0.f;
    __syncthreads();

    // interest: 8 rows x 8 col-groups per wave-op, wide LDS reads
    int cg = lane & 7;   // cols cg*8..+7
    int tg = lane >> 3;  // row within 8-row group
    float acc8[8];
    #pragma unroll
    for (int u = 0; u < 8; ++u) acc8[u] = 0.f;
    for (int t = wv * 8 + tg; t < TP; t += 32) {
        float w = s_sc[t];
        short8 h = ld8sw(s_hist, t, cg * 8);
        #pragma unroll
        for (int u = 0; u < 8; ++u) acc8[u] += w * b2f((unsigned short)h[u]);
    }
    #pragma unroll
    for (int u = 0; u < 8; ++u) {
        acc8[u] += __shfl_xor(acc8[u], 8);
        acc8[u] += __shfl_xor(acc8[u], 16);
        acc8[u] += __shfl_xor(acc8[u], 32);
    }
    if (tg == 0) {
        #pragma unroll
        for (int u = 0; u < 8; ++u) s_intp[wv][cg * 8 + u] = acc8[u];
    }
    __syncthreads();
    if (tid < 64)
        inter64[(long)b * 64 + tid] = s_intp[0][tid] + s_intp[1][tid] + s_intp[2][tid] + s_intp[3][tid];
}

// ---------------- KA fallback (round-5 proven path, used if ws too small) ----------------
extern "C" __global__ __launch_bounds__(256, 3) void k_attn_fb(
    const int* __restrict__ target, const int* __restrict__ hist,
    const int* __restrict__ mask,
    const float* __restrict__ embed, const float* __restrict__ aw1,
    const float* __restrict__ ab1, const float* __restrict__ aw2,
    const float* __restrict__ ab2, const float* __restrict__ aow,
    const float* __restrict__ aob,
    float* __restrict__ inter64)
{
    __shared__ int s_id[TP];
    __shared__ float s_q[64];
    __shared__ float s_qc[64];
    __shared__ float s_qcp[4][64];
    __shared__ alignas(16) unsigned short s_hist[TP * 64];
    __shared__ alignas(16) unsigned short s_WeffT[64 * 64];
    __shared__ alignas(16) unsigned short s_aw2T[32 * 64];
    __shared__ alignas(16) unsigned short s_h1[4 * 16 * 64];
    __shared__ float s_sc[TP];
    __shared__ float s_aow[32];
    __shared__ float s_ab2[32];
    __shared__ float s_red[8];
    __shared__ float s_intp[4][64];

    int tid = threadIdx.x;
    int lane = tid & 63;
    int wv = tid >> 6;
    int b = blockIdx.x;

    int tgt = target[b];
    if (tid < 64) s_q[tid] = embed[(long)tgt * 64 + tid];
    for (int t = tid; t < TP; t += 256) s_id[t] = hist[b * Tq + ((t < Tq) ? t : 0)];
    if (tid < 32) { s_aow[tid] = aow[tid]; s_ab2[tid] = ab2[tid]; }
    __syncthreads();

    for (int idx = tid; idx < 4096; idx += 256) {
        int i = idx >> 6, j = idx & 63;
        float w = aw1[i * 64 + j] + aw1[(128 + i) * 64 + j] + s_q[i] * aw1[(192 + i) * 64 + j];
        st16sw(s_WeffT, j, i, f2b(w));
    }
    for (int idx = tid; idx < 2048; idx += 256) {
        int j = idx >> 5, k = idx & 31;
        st16sw(s_aw2T, k, j, f2b(aw2[j * 32 + k]));
    }
    {
        float acc = 0.f;
        #pragma unroll
        for (int ii = 0; ii < 16; ++ii) {
            int i = wv * 16 + ii;
            acc += s_q[i] * (aw1[(64 + i) * 64 + lane] - aw1[(128 + i) * 64 + lane]);
        }
        s_qcp[wv][lane] = acc;
    }
    for (int u = tid; u < TP * 16; u += 256) {
        int t = u >> 4, j4 = u & 15;
        f32x4 e = *(const f32x4*)&embed[(long)s_id[t] * 64 + j4 * 4];
        bfx4 p = { f2b(e.x), f2b(e.y), f2b(e.z), f2b(e.w) };
        st64sw(s_hist, t, j4, p);
    }
    __syncthreads();
    if (tid < 64) s_qc[tid] = ab1[tid] + s_qcp[0][tid] + s_qcp[1][tid] + s_qcp[2][tid] + s_qcp[3][tid];
    __syncthreads();

    int r16 = lane & 15;
    int kg = lane >> 4;
    float aob0 = aob[0];
    unsigned short* h1w = s_h1 + wv * 16 * 64;

    for (int m = wv; m < NMT; m += 4) {
        int row0 = m * 16;
        short8 a0 = ld8sw(s_hist, row0 + r16, kg * 8);
        short8 a1 = ld8sw(s_hist, row0 + r16, 32 + kg * 8);
        f32x4 d[4];
        #pragma unroll
        for (int n = 0; n < 4; ++n) {
            short8 b0 = ld8sw(s_WeffT, n * 16 + r16, kg * 8);
            short8 b1 = ld8sw(s_WeffT, n * 16 + r16, 32 + kg * 8);
            float qcv = s_qc[n * 16 + r16];
            f32x4 z = { qcv, qcv, qcv, qcv };
            z = __builtin_amdgcn_mfma_f32_16x16x32_bf16(a0, b0, z, 0, 0, 0);
            z = __builtin_amdgcn_mfma_f32_16x16x32_bf16(a1, b1, z, 0, 0, 0);
            d[n] = z;
        }
        #pragma unroll
        for (int n = 0; n < 4; ++n) {
            int col = n * 16 + r16;
            #pragma unroll
            for (int r = 0; r < 4; ++r)
                st16sw(h1w, kg * 4 + r, col, f2b(fmaxf(d[n][r], 0.f)));
        }
        short8 ha0 = ld8sw(h1w, r16, kg * 8);
        short8 ha1 = ld8sw(h1w, r16, 32 + kg * 8);
        f32x4 e[2];
        #pragma unroll
        for (int n = 0; n < 2; ++n) {
            short8 b0 = ld8sw(s_aw2T, n * 16 + r16, kg * 8);
            short8 b1 = ld8sw(s_aw2T, n * 16 + r16, 32 + kg * 8);
            f32x4 z = { 0.f, 0.f, 0.f, 0.f };
            z = __builtin_amdgcn_mfma_f32_16x16x32_bf16(ha0, b0, z, 0, 0, 0);
            z = __builtin_amdgcn_mfma_f32_16x16x32_bf16(ha1, b1, z, 0, 0, 0);
            e[n] = z;
        }
        #pragma unroll
        for (int r = 0; r < 4; ++r) {
            float h20 = fmaxf(e[0][r] + s_ab2[r16], 0.f);
            float h21 = fmaxf(e[1][r] + s_ab2[16 + r16], 0.f);
            float p = h20 * s_aow[r16] + h21 * s_aow[16 + r16];
            p += __shfl_xor(p, 1);
            p += __shfl_xor(p, 2);
            p += __shfl_xor(p, 4);
            p += __shfl_xor(p, 8);
            if (r16 == 0) s_sc[row0 + kg * 4 + r] = p + aob0;
        }
    }
    __syncthreads();

    float sc = -1e30f;
    if (tid < Tq) {
        int mk = mask[(long)b * Tq + tid];
        sc = mk ? s_sc[tid] : -1e9f;
    }
    float mx = sc;
    #pragma unroll
    for (int off = 1; off < 64; off <<= 1) mx = fmaxf(mx, __shfl_xor(mx, off));
    if (lane == 0) s_red[wv] = mx;
    __syncthreads();
    mx = fmaxf(fmaxf(s_red[0], s_red[1]), fmaxf(s_red[2], s_red[3]));
    float ex = (tid < Tq) ? expf(sc - mx) : 0.f;
    float sm = ex;
    #pragma unroll
    for (int off = 1; off < 64; off <<= 1) sm += __shfl_xor(sm, off);
    if (lane == 0) s_red[4 + wv] = sm;
    __syncthreads();
    float tot = s_red[4] + s_red[5] + s_red[6] + s_red[7];
    if (tid < Tq) s_sc[tid] = ex / tot;
    __syncthreads();

    float acc = 0.f;
    for (int t = wv; t < Tq; t += 4)
        acc += s_sc[t] * b2f(*(const unsigned short*)((const char*)s_hist +
                 (((t << 7) + (lane << 1)) ^ ((t & 7) << 4))));
    s_intp[wv][lane] = acc;
    __syncthreads();
    if (tid < 64)
        inter64[(long)b * 64 + tid] = s_intp[0][tid] + s_intp[1][tid] + s_intp[2][tid] + s_intp[3][tid];
}

// ---------------- KB: final MLP [q | interest] 128->256->128->1, fp32, 8 rows/block ----------------
extern "C" __global__ __launch_bounds__(256) void k_final(
    const int* __restrict__ target, const float* __restrict__ embed,
    const float* __restrict__ inter64, const float* __restrict__ mw1,
    const float* __restrict__ mb1, const float* __restrict__ mw2,
    const float* __restrict__ mb2, const float* __restrict__ ow,
    const float* __restrict__ ob, float* __restrict__ out)
{
    __shared__ alignas(16) float s_in[8][128];
    __shared__ alignas(16) float s_g1[8][256];
    __shared__ alignas(16) float s_g2[8][128];
    int tid = threadIdx.x;
    long b0 = (long)blockIdx.x * 8;
    for (int idx = tid; idx < 1024; idx += 256) {
        int r = idx >> 7, c = idx & 127;
        s_in[r][c] = (c < 64) ? embed[(long)target[b0 + r] * 64 + c]
                              : inter64[(b0 + r) * 64 + (c - 64)];
    }
    __syncthreads();
    {
        float acc[8];
        float bias = mb1[tid];
        #pragma unroll
        for (int r = 0; r < 8; ++r) acc[r] = bias;
        for (int i0 = 0; i0 < 128; i0 += 4) {
            float w0 = mw1[(i0 + 0) * 256 + tid];
            float w1 = mw1[(i0 + 1) * 256 + tid];
            float w2 = mw1[(i0 + 2) * 256 + tid];
            float w3 = mw1[(i0 + 3) * 256 + tid];
            #pragma unroll
            for (int r = 0; r < 8; ++r) {
                f32x4 e = *(const f32x4*)&s_in[r][i0];
                acc[r] += e.x * w0 + e.y * w1 + e.z * w2 + e.w * w3;
            }
        }
        #pragma unroll
        for (int r = 0; r < 8; ++r) s_g1[r][tid] = fmaxf(acc[r], 0.f);
    }
    __syncthreads();
    {
        int o = tid & 127, rh = tid >> 7;
        float acc[4];
        float bias = mb2[o];
        #pragma unroll
        for (int r = 0; r < 4; ++r) acc[r] = bias;
        for (int i0 = 0; i0 < 256; i0 += 4) {
            float w0 = mw2[(i0 + 0) * 128 + o];
            float w1 = mw2[(i0 + 1) * 128 + o];
            float w2 = mw2[(i0 + 2) * 128 + o];
            float w3 = mw2[(i0 + 3) * 128 + o];
            #pragma unroll
            for (int r = 0; r < 4; ++r) {
                f32x4 e = *(const f32x4*)&s_g1[rh * 4 + r][i0];
                acc[r] += e.x * w0 + e.y * w1 + e.z * w2 + e.w * w3;
            }
        }
        #pragma unroll
        for (int r = 0; r < 4; ++r) s_g2[rh * 4 + r][o] = fmaxf(acc[r], 0.f);
    }
    __syncthreads();
    {
        int r = tid >> 5, l32 = tid & 31;
        float acc = 0.f;
        #pragma unroll
        for (int k = 0; k < 4; ++k) acc += s_g2[r][l32 + k * 32] * ow[l32 + k * 32];
        acc += __shfl_xor(acc, 1);
        acc += __shfl_xor(acc, 2);
        acc += __shfl_xor(acc, 4);
        acc += __shfl_xor(acc, 8);
        acc += __shfl_xor(acc, 16);
        if (l32 == 0) out[b0 + r] = acc + ob[0];
    }
}

extern "C" void kernel_launch(void* const* d_in, const int* in_sizes, int n_in,
                              void* d_out, int out_size, void* d_ws, size_t ws_size,
                              hipStream_t stream)
{
    const int*   target = (const int*)d_in[0];
    const int*   hist   = (const int*)d_in[1];
    const int*   mask   = (const int*)d_in[2];
    const float* embed  = (const float*)d_in[3];
    const float* aw1    = (const float*)d_in[4];
    const float* ab1    = (const float*)d_in[5];
    const float* aw2    = (const float*)d_in[6];
    const float* ab2    = (const float*)d_in[7];
    const float* aow    = (const float*)d_in[8];
    const float* aob    = (const float*)d_in[9];
    const float* mw1    = (const float*)d_in[10];
    const float* mb1    = (const float*)d_in[11];
    const float* mw2    = (const float*)d_in[12];
    const float* mb2    = (const float*)d_in[13];
    const float* ow     = (const float*)d_in[14];
    const float* ob     = (const float*)d_in[15];
    float* out = (float*)d_out;

    const size_t WEFF_B = (size_t)Bq * 4096 * 2;     // 32 MB
    const size_t QC_B   = (size_t)Bq * 64 * 4;       // 1 MB
    const size_t AW2T_B = 4096;                      // 4 KB
    const size_t EMBF_B = (size_t)Vq * 64 * 2;       // 12.8 MB
    const size_t INT_B  = (size_t)Bq * 64 * 4;       // 1 MB
    char* p = (char*)d_ws;

    if (ws_size >= WEFF_B + QC_B + AW2T_B + EMBF_B + INT_B) {
        unsigned short* weff  = (unsigned short*)p;
        float*          qc    = (float*)(p + WEFF_B);
        unsigned short* aw2t  = (unsigned short*)(p + WEFF_B + QC_B);
        unsigned short* embf  = (unsigned short*)(p + WEFF_B + QC_B + AW2T_B);
        float*          inter = (float*)(p + WEFF_B + QC_B + AW2T_B + EMBF_B);
        k_weff<<<Bq / BPB, 256, 0, stream>>>(target, embed, aw1, ab1, aw2, weff, qc, aw2t, embf);
        k_attn_fast<<<Bq, 256, 0, stream>>>(hist, mask, embed, ab2, aow, aob,
                                            weff, qc, aw2t, embf, inter);
        k_final<<<Bq / 8, 256, 0, stream>>>(target, embed, inter, mw1, mb1, mw2,
                                            mb2, ow, ob, out);
    } else {
        float* inter = (float*)p;                    // 1 MB
        k_attn_fb<<<Bq, 256, 0, stream>>>(target, hist, mask, embed, aw1, ab1,
                                          aw2, ab2, aow, aob, inter);
        k_final<<<Bq / 8, 256, 0, stream>>>(target, embed, inter, mw1, mb1, mw2,
                                            mb2, ow, ob, out);
    }
}